// Round 1
// baseline (450.807 us; speedup 1.0000x reference)
//
#include <hip/hip_runtime.h>
#include <cstdint>

#define Bb 4
#define Lseq 4096
#define Hh 1024
#define Nst 64
constexpr float LN_EPS = 1e-5f;

// ---------------------------------------------------------------------------
// K1: transpose x [B, L, H] -> xt [B, H, L] (into ws). LDS 32x33 tile,
// coalesced 128B rows both directions, bank-conflict-free (stride 33).
// ---------------------------------------------------------------------------
__global__ __launch_bounds__(256) void k_transpose(const float* __restrict__ x,
                                                   float* __restrict__ xt) {
    __shared__ float tile[32][33];
    const int h0 = blockIdx.x * 32;
    const int l0 = blockIdx.y * 32;
    const int b  = blockIdx.z;
    const int tj = threadIdx.x & 31;
    const int ti = threadIdx.x >> 5;  // 0..7

    const float* src = x + ((size_t)b * Lseq + l0) * Hh + h0;
#pragma unroll
    for (int it = 0; it < 4; ++it) {
        int row = it * 8 + ti;                       // l offset
        tile[row][tj] = src[(size_t)row * Hh + tj];  // x[b, l0+row, h0+tj]
    }
    __syncthreads();
    float* dst = xt + ((size_t)b * Hh + h0) * Lseq + l0;
#pragma unroll
    for (int it = 0; it < 4; ++it) {
        int row = it * 8 + ti;                       // h offset
        dst[(size_t)row * Lseq + tj] = tile[tj][row];  // xt[b,h0+row,l0+tj]
    }
}

// ---------------------------------------------------------------------------
// K2: diagonal-SSM scan. One wave64 per (b,h); lane = mode n (N=64).
//   s = w*s + x  (complex, per lane), contrib = 2*Re(Ct * s)
//   y[l] = sum over lanes -> via LDS tile [64 steps][65] transposed row-sum.
// Writes r = x*(1+D) + y in-place over xt (same addresses it just read).
// Block = 128 threads (2 waves) -> 33,280 B LDS -> 4 blocks/CU, 8 waves/CU.
// ---------------------------------------------------------------------------
__global__ __launch_bounds__(128) void k_scan(float* __restrict__ xt,
                                              const float* __restrict__ logA,
                                              const float* __restrict__ Aim,
                                              const float* __restrict__ Cre,
                                              const float* __restrict__ Cim,
                                              const float* __restrict__ logdt,
                                              const float* __restrict__ Dp) {
    __shared__ float tile[2][64 * 65];
    const int w    = threadIdx.x >> 6;
    const int lane = threadIdx.x & 63;
    const int g    = blockIdx.x * 2 + w;   // global wave id = b*H + h
    const int b    = g >> 10;              // / H
    const int h    = g & (Hh - 1);
    const int idx  = h * Nst + lane;

    // --- per-(h,n) constants (setup, once per wave) ---
    const float ar  = -expf(logA[idx]);
    const float ai  = Aim[idx];
    const float dt  = expf(logdt[h]);
    const float dAr = dt * ar, dAi = dt * ai;
    const float em  = expf(dAr);
    const float wr  = em * cosf(dAi);
    const float wi  = em * sinf(dAi);
    // E = exp(dtA) - 1 = (wr-1) + i*wi ;  Ct = C*E/A = C*E*conj(A)/|A|^2
    const float Er = wr - 1.0f, Ei = wi;
    const float cr = Cre[idx], ci = Cim[idx];
    const float nr = cr * Er - ci * Ei;
    const float ni = cr * Ei + ci * Er;
    const float invd = 1.0f / (ar * ar + ai * ai);
    const float Ctr = (nr * ar + ni * ai) * invd;
    const float Cti = (ni * ar - nr * ai) * invd;
    const float gr = 2.0f * Ctr, gi = -2.0f * Cti;   // y += gr*sr + gi*si
    const float Dp1 = 1.0f + Dp[h];

    float* wt   = tile[w];
    float* xrow = xt + (size_t)g * Lseq;

    float sr = 0.0f, si = 0.0f;
    for (int l0 = 0; l0 < Lseq; l0 += 64) {
        const float xv = xrow[l0 + lane];  // coalesced 256B per wave
#pragma unroll
        for (int t = 0; t < 64; ++t) {
            // broadcast x[l0+t] to all lanes via readlane (SGPR)
            const float xs = __int_as_float(
                __builtin_amdgcn_readlane(__float_as_int(xv), t));
            const float t1 = wi * sr;
            sr = fmaf(wr, sr, fmaf(-wi, si, xs));
            si = fmaf(wr, si, t1);
            // tile[t][lane]: bank = (t+lane)%32 -> 2-way (free)
            wt[t * 65 + lane] = fmaf(gi, si, gr * sr);
        }
        __syncthreads();
        // lane j sums row j -> y[l0+j]; bank = (j+k)%32 -> 2-way (free)
        const float* row = wt + lane * 65;
        float a0 = 0.f, a1 = 0.f, a2 = 0.f, a3 = 0.f;
#pragma unroll
        for (int k = 0; k < 64; k += 4) {
            a0 += row[k];
            a1 += row[k + 1];
            a2 += row[k + 2];
            a3 += row[k + 3];
        }
        const float y = (a0 + a1) + (a2 + a3);
        // r = x*(1+D) + y, in-place (same addresses this wave just read)
        xrow[l0 + lane] = fmaf(xv, Dp1, y);
        __syncthreads();
    }
}

// ---------------------------------------------------------------------------
// K3: LayerNorm over H + transpose back: rt [B,H,L] -> out [B,L,H].
// Block = 256 threads handles (b, 32 consecutive l).
// Pass A: stream all H rows, per-l sum/sumsq. Pass B: re-read in 256-h chunks
// through padded LDS tile, write out[b,l,:] coalesced (1KB per store op).
// ---------------------------------------------------------------------------
__global__ __launch_bounds__(256) void k_ln(const float* __restrict__ rt,
                                            float* __restrict__ out,
                                            const float* __restrict__ lnw,
                                            const float* __restrict__ lnb) {
    __shared__ float tile[256 * 33];
    __shared__ float ps[8][32], pq[8][32];
    __shared__ float mm[32], rs[32];
    const int b  = blockIdx.y;
    const int l0 = blockIdx.x * 32;
    const int ll = threadIdx.x & 31;
    const int hh = threadIdx.x >> 5;  // 0..7

    const float* base = rt + (size_t)b * Hh * Lseq + l0;

    // ---- pass A: per-l mean/var over all H ----
    float psum = 0.0f, psq = 0.0f;
#pragma unroll 8
    for (int hc = 0; hc < Hh; hc += 8) {
        const float v = base[(size_t)(hc + hh) * Lseq + ll];
        psum += v;
        psq = fmaf(v, v, psq);
    }
    ps[hh][ll] = psum;
    pq[hh][ll] = psq;
    __syncthreads();
    if (threadIdx.x < 32) {
        float s = 0.f, q = 0.f;
#pragma unroll
        for (int k = 0; k < 8; ++k) {
            s += ps[k][threadIdx.x];
            q += pq[k][threadIdx.x];
        }
        const float mu  = s * (1.0f / Hh);
        const float var = fmaf(-mu, mu, q * (1.0f / Hh));
        mm[threadIdx.x] = mu;
        rs[threadIdx.x] = rsqrtf(var + LN_EPS);
    }
    __syncthreads();

    // ---- pass B: normalize + transpose to [B,L,H] ----
    for (int hc = 0; hc < Hh; hc += 256) {
#pragma unroll
        for (int it = 0; it < 32; ++it) {
            const int hrow = it * 8 + hh;
            tile[hrow * 33 + ll] = base[(size_t)(hc + hrow) * Lseq + ll];
        }
        const float w  = lnw[hc + threadIdx.x];
        const float bo = lnb[hc + threadIdx.x];
        __syncthreads();
        float* orow = out + ((size_t)b * Lseq + l0) * Hh + hc + threadIdx.x;
#pragma unroll
        for (int l = 0; l < 32; ++l) {
            const float v = tile[threadIdx.x * 33 + l];  // bank (tid+l)%32: 2-way
            orow[(size_t)l * Hh] = fmaf((v - mm[l]) * rs[l], w, bo);
        }
        __syncthreads();
    }
}

// ---------------------------------------------------------------------------
extern "C" void kernel_launch(void* const* d_in, const int* in_sizes, int n_in,
                              void* d_out, int out_size, void* d_ws, size_t ws_size,
                              hipStream_t stream) {
    const float* x     = (const float*)d_in[0];
    const float* logA  = (const float*)d_in[1];
    const float* Aim   = (const float*)d_in[2];
    const float* Cre   = (const float*)d_in[3];
    const float* Cim   = (const float*)d_in[4];
    const float* logdt = (const float*)d_in[5];
    const float* Dp    = (const float*)d_in[6];
    const float* lnw   = (const float*)d_in[7];
    const float* lnb   = (const float*)d_in[8];
    float* out = (float*)d_out;
    float* ws  = (float*)d_ws;  // needs B*L*H*4 = 64 MiB

    // K1: x -> ws (transposed [B,H,L])
    k_transpose<<<dim3(Hh / 32, Lseq / 32, Bb), 256, 0, stream>>>(x, ws);
    // K2: scan, ws in-place becomes r_t [B,H,L]
    k_scan<<<dim3(Bb * Hh / 2), 128, 0, stream>>>(ws, logA, Aim, Cre, Cim, logdt, Dp);
    // K3: LN + transpose back -> out [B,L,H]
    k_ln<<<dim3(Lseq / 32, Bb), 256, 0, stream>>>(ws, out, lnw, lnb);
}

// Round 2
// 269.452 us; speedup vs baseline: 1.6731x; 1.6731x over previous
//
#include <hip/hip_runtime.h>
#include <cstdint>

#define Bb 4
#define Lseq 4096
#define Hh 1024
#define Nst 64
constexpr float LN_EPS = 1e-5f;

typedef _Float16 f16x8 __attribute__((ext_vector_type(8)));
typedef _Float16 f16x4 __attribute__((ext_vector_type(4)));
typedef float f32x4v __attribute__((ext_vector_type(4)));

// ---------------------------------------------------------------------------
// K0: precompute per-h 64x64 matrices (f16) into d_out scratch:
//   layout per h (5*4096 f16): [U_re | U_im | M1 (Tril K) | P_re | P_im_neg]
//   U[n][j]  = w_n^{63-j}
//   M1[t][j] = K[t-j] (j<=t), K[tau] = 2 Re sum_n Ct_n w_n^tau
//   P[t][n]  = Re/(-Im) of 2*Ct_n*w_n^{t+1}
// plus ww = w^64 (fp32) for the chunk-level scan.
// ---------------------------------------------------------------------------
__global__ __launch_bounds__(256) void k_precompute(
    const float* __restrict__ logA, const float* __restrict__ Aim,
    const float* __restrict__ Cre, const float* __restrict__ Cim,
    const float* __restrict__ logdt, _Float16* __restrict__ mats,
    float* __restrict__ wwR, float* __restrict__ wwI) {
    __shared__ float sdAr[64], sdAi[64], scR[64], scI[64], sK[64];
    const int h = blockIdx.x, tid = threadIdx.x;
    _Float16* g = mats + (size_t)h * 20480;

    if (tid < 64) {
        const int n = tid, idx = h * 64 + n;
        const float ar = -expf(logA[idx]), ai = Aim[idx];
        const float dt = expf(logdt[h]);
        const float dAr = dt * ar, dAi = dt * ai;
        const float em = expf(dAr);
        const float wr = em * cosf(dAi), wi = em * sinf(dAi);
        const float Er = wr - 1.0f, Ei = wi;
        const float cr = Cre[idx], ci = Cim[idx];
        const float nr = cr * Er - ci * Ei, ni = cr * Ei + ci * Er;
        const float invd = 1.0f / (ar * ar + ai * ai);
        const float CtR = (nr * ar + ni * ai) * invd;
        const float CtI = (ni * ar - nr * ai) * invd;
        sdAr[n] = dAr; sdAi[n] = dAi; scR[n] = 2.0f * CtR; scI[n] = 2.0f * CtI;
        const float e64 = expf(dAr * 64.0f), a64 = dAi * 64.0f;
        wwR[idx] = e64 * cosf(a64);
        wwI[idx] = e64 * sinf(a64);
    }
    __syncthreads();

    // U (row=n, col=j) and P (row=t, col=n)
    for (int e = tid; e < 4096; e += 256) {
        const int row = e >> 6, colj = e & 63;
        {
            const float p = (float)(63 - colj);
            const float ee = expf(sdAr[row] * p), ang = sdAi[row] * p;
            g[e]        = (_Float16)(ee * cosf(ang));
            g[4096 + e] = (_Float16)(ee * sinf(ang));
        }
        {
            const int n = colj;
            const float q = (float)(row + 1);
            const float ee = expf(sdAr[n] * q), ang = sdAi[n] * q;
            const float wRq = ee * cosf(ang), wIq = ee * sinf(ang);
            g[12288 + e] = (_Float16)(scR[n] * wRq - scI[n] * wIq);
            g[16384 + e] = (_Float16)(-(scR[n] * wIq + scI[n] * wRq));
        }
    }
    // K[tau]
    if (tid < 64) {
        const float tau = (float)tid;
        float sum = 0.0f;
        for (int n = 0; n < 64; ++n) {
            const float ee = expf(sdAr[n] * tau), ang = sdAi[n] * tau;
            sum += ee * (scR[n] * cosf(ang) - scI[n] * sinf(ang));
        }
        sK[tid] = sum;
    }
    __syncthreads();
    // M1 Toeplitz
    for (int e = tid; e < 4096; e += 256) {
        const int t = e >> 6, j = e & 63;
        g[8192 + e] = (j <= t) ? (_Float16)sK[t - j] : (_Float16)0.0f;
    }
}

// ---------------------------------------------------------------------------
// K1: transpose x [B, L, H] -> xt [B, H, L] (into ws).
// ---------------------------------------------------------------------------
__global__ __launch_bounds__(256) void k_transpose(const float* __restrict__ x,
                                                   float* __restrict__ xt) {
    __shared__ float tile[32][33];
    const int h0 = blockIdx.x * 32;
    const int l0 = blockIdx.y * 32;
    const int b  = blockIdx.z;
    const int tj = threadIdx.x & 31;
    const int ti = threadIdx.x >> 5;

    const float* src = x + ((size_t)b * Lseq + l0) * Hh + h0;
#pragma unroll
    for (int it = 0; it < 4; ++it) {
        int row = it * 8 + ti;
        tile[row][tj] = src[(size_t)row * Hh + tj];
    }
    __syncthreads();
    float* dst = xt + ((size_t)b * Hh + h0) * Lseq + l0;
#pragma unroll
    for (int it = 0; it < 4; ++it) {
        int row = it * 8 + ti;
        dst[(size_t)row * Lseq + tj] = tile[tj][row];
    }
}

// ---------------------------------------------------------------------------
// K2: chunked block-scan via MFMA. One block (4 waves) per (b,h).
//   phase 1: u[c][n] = X[c][:] @ U[n][:]   (complex, 2 matmuls)
//   phase 2: 64-step chunk scan S_{c+1} = ww*S_c + u_c (fp32, waves 0-1),
//            waves 2-3 stage M1/PR; then stage PIneg.
//   phase 3: y = X@M1^T + SR@PR^T + SI@PIneg^T (3 accumulated matmuls)
//   epilogue: r = x*(1+D) + y  written in-place over xt.
// LDS arena 64,512 B -> 2 blocks/CU.
// ---------------------------------------------------------------------------
#define XBF   0        // f16 [64][72]
#define SRBF  9216     // f16 [64][72]
#define SIBF  18432    // f16 [64][72]
#define URo   27648    // f16 [64][72]  (phase2: M1)
#define UIo   36864    // f16 [64][72]  (phase2: PR)
#define uRh   46080    // f16 [64][72]  (phase2b: PIneg)
#define uIh   55296    // f16 [64][72]  (phase3: YF f16 [64][72])
#define M1o   27648
#define PRo   36864
#define PIo   46080
#define YFo   55296

#define AFRAG(base, row0) \
    (*(const f16x8*)(sm + (base) + ((row0) + (lane & 15)) * 144 + kh * 2 + ((lane >> 4) << 4)))

__global__ __launch_bounds__(256, 2) void k_chunk(
    float* __restrict__ xt, const _Float16* __restrict__ mats,
    const float* __restrict__ wwR, const float* __restrict__ wwI,
    const float* __restrict__ Dp) {
    __shared__ __align__(16) unsigned char sm[64512];
    const int tid = threadIdx.x, lane = tid & 63, wv = tid >> 6;
    const int bx = blockIdx.x, h = bx & (Hh - 1), b = bx >> 10;
    float* xr = xt + (size_t)(b * Hh + h) * Lseq;
    const _Float16* g = mats + (size_t)h * 20480;
    const int col = lane & 15, qd = lane >> 4;
    const int band = wv * 16;

    // ---- stage X (fp32 -> f16) ----
#pragma unroll
    for (int r = 0; r < 4; ++r) {
        const int idx = r * 1024 + tid * 4;
        const float4 v = *(const float4*)(xr + idx);
        const int c = idx >> 6, j = idx & 63;
        f16x4 hv;
        hv[0] = (_Float16)v.x; hv[1] = (_Float16)v.y;
        hv[2] = (_Float16)v.z; hv[3] = (_Float16)v.w;
        *(f16x4*)(sm + XBF + c * 144 + j * 2) = hv;
    }
    // ---- stage UR + UI ----
#pragma unroll
    for (int r = 0; r < 4; ++r) {
        const int e = r * 2048 + tid * 8;   // 0..8191
        const int m = e >> 12, e2 = e & 4095;
        const int row = e2 >> 6, cc = e2 & 63;
        *(uint4*)(sm + (m ? UIo : URo) + row * 144 + cc * 2) =
            *(const uint4*)(g + e);
    }
    __syncthreads();

    // ---- phase 1: u = X @ U^T (complex) ----
    f32x4v aR[4] = {}, aI[4] = {};
#pragma unroll
    for (int kh = 0; kh < 64; kh += 32) {
        const f16x8 ax = AFRAG(XBF, band);
#pragma unroll
        for (int nt = 0; nt < 4; ++nt) {
            aR[nt] = __builtin_amdgcn_mfma_f32_16x16x32_f16(
                ax, AFRAG(URo, nt * 16), aR[nt], 0, 0, 0);
            aI[nt] = __builtin_amdgcn_mfma_f32_16x16x32_f16(
                ax, AFRAG(UIo, nt * 16), aI[nt], 0, 0, 0);
        }
    }
#pragma unroll
    for (int nt = 0; nt < 4; ++nt)
#pragma unroll
        for (int rg = 0; rg < 4; ++rg) {
            const int c = band + qd * 4 + rg, n = nt * 16 + col;
            *(_Float16*)(sm + uRh + c * 144 + n * 2) = (_Float16)aR[nt][rg];
            *(_Float16*)(sm + uIh + c * 144 + n * 2) = (_Float16)aI[nt][rg];
        }
    __syncthreads();

    // ---- phase 2: chunk scan (waves 0-1) | stage M1/PR (waves 2-3) ----
    if (wv < 2) {
        const int n = wv * 32 + (lane & 31);
        const float wR = wwR[h * 64 + n], wI = wwI[h * 64 + n];
        float sR = 0.0f, sI = 0.0f;
        for (int c = 0; c < 64; ++c) {
            if (lane < 32) {
                *(_Float16*)(sm + SRBF + c * 144 + n * 2) = (_Float16)sR;
                *(_Float16*)(sm + SIBF + c * 144 + n * 2) = (_Float16)sI;
            }
            const float uRv = (float)*(const _Float16*)(sm + uRh + c * 144 + n * 2);
            const float uIv = (float)*(const _Float16*)(sm + uIh + c * 144 + n * 2);
            const float nR = fmaf(wR, sR, fmaf(-wI, sI, uRv));
            sI = fmaf(wR, sI, fmaf(wI, sR, uIv));
            sR = nR;
        }
    } else {
        const _Float16* gs = g + (wv == 2 ? 8192 : 12288);
        unsigned char* dst = sm + (wv == 2 ? M1o : PRo);
#pragma unroll
        for (int r = 0; r < 8; ++r) {
            const int e = r * 512 + lane * 8;
            const int row = e >> 6, cc = e & 63;
            *(uint4*)(dst + row * 144 + cc * 2) = *(const uint4*)(gs + e);
        }
    }
    __syncthreads();
    // ---- stage PIneg (all threads; overwrites dead uRh) ----
#pragma unroll
    for (int r = 0; r < 2; ++r) {
        const int e = r * 2048 + tid * 8;
        const int row = e >> 6, cc = e & 63;
        *(uint4*)(sm + PIo + row * 144 + cc * 2) = *(const uint4*)(g + 16384 + e);
    }
    __syncthreads();

    // ---- phase 3: y = X@M1^T + SR@PR^T + SI@PIneg^T ----
    f32x4v acc[4] = {};
#pragma unroll
    for (int kh = 0; kh < 64; kh += 32) {
        const f16x8 ax = AFRAG(XBF, band);
#pragma unroll
        for (int tt = 0; tt < 4; ++tt)
            acc[tt] = __builtin_amdgcn_mfma_f32_16x16x32_f16(
                ax, AFRAG(M1o, tt * 16), acc[tt], 0, 0, 0);
    }
#pragma unroll
    for (int kh = 0; kh < 64; kh += 32) {
        const f16x8 as = AFRAG(SRBF, band);
#pragma unroll
        for (int tt = 0; tt < 4; ++tt)
            acc[tt] = __builtin_amdgcn_mfma_f32_16x16x32_f16(
                as, AFRAG(PRo, tt * 16), acc[tt], 0, 0, 0);
    }
#pragma unroll
    for (int kh = 0; kh < 64; kh += 32) {
        const f16x8 az = AFRAG(SIBF, band);
#pragma unroll
        for (int tt = 0; tt < 4; ++tt)
            acc[tt] = __builtin_amdgcn_mfma_f32_16x16x32_f16(
                az, AFRAG(PIo, tt * 16), acc[tt], 0, 0, 0);
    }
    // store y (f16) to YFo
#pragma unroll
    for (int tt = 0; tt < 4; ++tt)
#pragma unroll
        for (int rg = 0; rg < 4; ++rg) {
            const int c = band + qd * 4 + rg, t = tt * 16 + col;
            *(_Float16*)(sm + YFo + c * 144 + t * 2) = (_Float16)acc[tt][rg];
        }
    __syncthreads();

    // ---- epilogue: r = x*(1+D) + y, in-place ----
    const float Dp1 = 1.0f + Dp[h];
#pragma unroll
    for (int r = 0; r < 4; ++r) {
        const int idx = r * 1024 + tid * 4;
        const int c = idx >> 6, j = idx & 63;
        const float4 xv = *(const float4*)(xr + idx);
        const f16x4 yv = *(const f16x4*)(sm + YFo + c * 144 + j * 2);
        float4 o;
        o.x = fmaf(xv.x, Dp1, (float)yv[0]);
        o.y = fmaf(xv.y, Dp1, (float)yv[1]);
        o.z = fmaf(xv.z, Dp1, (float)yv[2]);
        o.w = fmaf(xv.w, Dp1, (float)yv[3]);
        *(float4*)(xr + idx) = o;
    }
}

// ---------------------------------------------------------------------------
// K3: LayerNorm over H + transpose back: rt [B,H,L] -> out [B,L,H].
// ---------------------------------------------------------------------------
__global__ __launch_bounds__(256) void k_ln(const float* __restrict__ rt,
                                            float* __restrict__ out,
                                            const float* __restrict__ lnw,
                                            const float* __restrict__ lnb) {
    __shared__ float tile[256 * 33];
    __shared__ float ps[8][32], pq[8][32];
    __shared__ float mm[32], rs[32];
    const int b  = blockIdx.y;
    const int l0 = blockIdx.x * 32;
    const int ll = threadIdx.x & 31;
    const int hh = threadIdx.x >> 5;

    const float* base = rt + (size_t)b * Hh * Lseq + l0;

    float psum = 0.0f, psq = 0.0f;
#pragma unroll 8
    for (int hc = 0; hc < Hh; hc += 8) {
        const float v = base[(size_t)(hc + hh) * Lseq + ll];
        psum += v;
        psq = fmaf(v, v, psq);
    }
    ps[hh][ll] = psum;
    pq[hh][ll] = psq;
    __syncthreads();
    if (threadIdx.x < 32) {
        float s = 0.f, q = 0.f;
#pragma unroll
        for (int k = 0; k < 8; ++k) {
            s += ps[k][threadIdx.x];
            q += pq[k][threadIdx.x];
        }
        const float mu  = s * (1.0f / Hh);
        const float var = fmaf(-mu, mu, q * (1.0f / Hh));
        mm[threadIdx.x] = mu;
        rs[threadIdx.x] = rsqrtf(var + LN_EPS);
    }
    __syncthreads();

    for (int hc = 0; hc < Hh; hc += 256) {
#pragma unroll
        for (int it = 0; it < 32; ++it) {
            const int hrow = it * 8 + hh;
            tile[hrow * 33 + ll] = base[(size_t)(hc + hrow) * Lseq + ll];
        }
        const float w  = lnw[hc + threadIdx.x];
        const float bo = lnb[hc + threadIdx.x];
        __syncthreads();
        float* orow = out + ((size_t)b * Lseq + l0) * Hh + hc + threadIdx.x;
#pragma unroll
        for (int l = 0; l < 32; ++l) {
            const float v = tile[threadIdx.x * 33 + l];
            orow[(size_t)l * Hh] = fmaf((v - mm[l]) * rs[l], w, bo);
        }
        __syncthreads();
    }
}

// ---------------------------------------------------------------------------
extern "C" void kernel_launch(void* const* d_in, const int* in_sizes, int n_in,
                              void* d_out, int out_size, void* d_ws, size_t ws_size,
                              hipStream_t stream) {
    const float* x     = (const float*)d_in[0];
    const float* logA  = (const float*)d_in[1];
    const float* Aim   = (const float*)d_in[2];
    const float* Cre   = (const float*)d_in[3];
    const float* Cim   = (const float*)d_in[4];
    const float* logdt = (const float*)d_in[5];
    const float* Dp    = (const float*)d_in[6];
    const float* lnw   = (const float*)d_in[7];
    const float* lnb   = (const float*)d_in[8];
    float* out = (float*)d_out;
    float* ws  = (float*)d_ws;  // 64 MiB: xt/r [B,H,L]

    // mats scratch inside d_out (dead until k_ln rewrites it):
    _Float16* mats = (_Float16*)d_out;                          // 40 MiB
    float* wwR = (float*)((char*)d_out + 41943040);             // 256 KiB
    float* wwI = (float*)((char*)d_out + 42205184);             // 256 KiB

    k_precompute<<<dim3(Hh), 256, 0, stream>>>(logA, Aim, Cre, Cim, logdt,
                                               mats, wwR, wwI);
    k_transpose<<<dim3(Hh / 32, Lseq / 32, Bb), 256, 0, stream>>>(x, ws);
    k_chunk<<<dim3(Bb * Hh), 256, 0, stream>>>(ws, mats, wwR, wwI, Dp);
    k_ln<<<dim3(Lseq / 32, Bb), 256, 0, stream>>>(ws, out, lnw, lnb);
}